// Round 1
// baseline (1932.034 us; speedup 1.0000x reference)
//
#include <hip/hip_runtime.h>
#include <math.h>

#define NN 50000
#define NE 800000
#define Cc 32
#define Zz 4
#define Bb 8
#define NL 2
#define DEG_INV (1.0f/16.0f)

__device__ __forceinline__ float ssp_f(float x) {
    // softplus(x) - log(2), numerically stable
    float sp = fmaxf(x, 0.0f) + log1pf(expf(-fabsf(x)));
    return sp - 0.69314718055994530942f;
}
__device__ __forceinline__ float silu_f(float x) {
    return x / (1.0f + expf(-x));
}

// s[n,f] = sum_c x[n,c] * W0[c,f]
// v[n,f,i] = sum_c x[n,32+c*3+i] * W1[c,f]
__global__ void node_pre_kernel(const float* __restrict__ x,
                                const float* __restrict__ W0,
                                const float* __restrict__ W1,
                                float* __restrict__ s,
                                float* __restrict__ v) {
    __shared__ float xs[8][128];
    int t = threadIdx.x;
    int node0 = blockIdx.x * 8;
    #pragma unroll
    for (int k = 0; k < 4; ++k) {
        int idx = t + k * 256;          // 0..1023
        int n = idx >> 7, col = idx & 127;
        int gn = node0 + n;
        if (gn < NN) xs[n][col] = x[gn * 128 + col];
    }
    __syncthreads();
    int n = t >> 5, f = t & 31;
    int gn = node0 + n;
    if (gn >= NN) return;
    float acc_s = 0.f, a0 = 0.f, a1 = 0.f, a2 = 0.f;
    #pragma unroll
    for (int c = 0; c < Cc; ++c) {
        float w0 = W0[c * Cc + f];
        float w1 = W1[c * Cc + f];
        acc_s = fmaf(xs[n][c], w0, acc_s);
        a0 = fmaf(xs[n][32 + c * 3 + 0], w1, a0);
        a1 = fmaf(xs[n][32 + c * 3 + 1], w1, a1);
        a2 = fmaf(xs[n][32 + c * 3 + 2], w1, a2);
    }
    s[gn * Cc + f] = acc_s;
    v[gn * 96 + f * 3 + 0] = a0;
    v[gn * 96 + f * 3 + 1] = a1;
    v[gn * 96 + f * 3 + 2] = a2;
}

// 32 lanes per edge; 8 edges per 256-thread block
__global__ void edge_kernel(const int* __restrict__ ei,
                            const float* __restrict__ emb,
                            const float* __restrict__ eattr,
                            const float* __restrict__ s,
                            const float* __restrict__ v,
                            const float* __restrict__ Wr1,
                            const float* __restrict__ Wr2,
                            float* __restrict__ agg_s,
                            float* __restrict__ agg_v) {
    int t = threadIdx.x;
    int eg = t >> 5;
    int c = t & 31;
    int e = blockIdx.x * 8 + eg;
    if (e >= NE) return;
    int src = ei[e];
    int dst = ei[NE + e];

    // h[j] = silu(sum_k emb[k]*Wr1[k,j]) computed on lanes 0..7
    float h = 0.f;
    if (c < 8) {
        #pragma unroll
        for (int k = 0; k < 8; ++k)
            h = fmaf(emb[e * 8 + k], Wr1[k * 8 + c], h);
        h = silu_f(h);
    }
    float w1 = 0.f, w2 = 0.f, w3 = 0.f, w4 = 0.f, w5 = 0.f;
    #pragma unroll
    for (int j = 0; j < 8; ++j) {
        float hj = __shfl(h, j, 32);
        const float* wr = Wr2 + j * 160;
        w1 = fmaf(hj, wr[c], w1);
        w2 = fmaf(hj, wr[32 + c], w2);
        w3 = fmaf(hj, wr[64 + c], w3);
        w4 = fmaf(hj, wr[96 + c], w4);
        w5 = fmaf(hj, wr[128 + c], w5);
    }
    float Y0  = eattr[e * 4 + 0];
    float Yv0 = eattr[e * 4 + 1];
    float Yv1 = eattr[e * 4 + 2];
    float Yv2 = eattr[e * 4 + 3];

    float se  = s[src * Cc + c];
    float ve0 = v[src * 96 + c * 3 + 0];
    float ve1 = v[src * 96 + c * 3 + 1];
    float ve2 = v[src * 96 + c * 3 + 2];

    float dot = ve0 * Yv0 + ve1 * Yv1 + ve2 * Yv2;
    float ms = (w1 * se * Y0 + w4 * dot) * DEG_INV;

    float cx = ve1 * Yv2 - ve2 * Yv1;
    float cy = ve2 * Yv0 - ve0 * Yv2;
    float cz = ve0 * Yv1 - ve1 * Yv0;

    float mv0 = (w2 * se * Yv0 + w3 * ve0 * Y0 + w5 * cx) * DEG_INV;
    float mv1 = (w2 * se * Yv1 + w3 * ve1 * Y0 + w5 * cy) * DEG_INV;
    float mv2 = (w2 * se * Yv2 + w3 * ve2 * Y0 + w5 * cz) * DEG_INV;

    atomicAdd(&agg_s[dst * Cc + c], ms);
    atomicAdd(&agg_v[dst * 96 + c * 3 + 0], mv0);
    atomicAdd(&agg_v[dst * 96 + c * 3 + 1], mv1);
    atomicAdd(&agg_v[dst * 96 + c * 3 + 2], mv2);
}

// per node: out_s (64), out_v (32x3), gating, residual update of x
__global__ void node_post_kernel(float* __restrict__ x,
                                 const float* __restrict__ attrs,
                                 const float* __restrict__ agg_s,
                                 const float* __restrict__ agg_v,
                                 const float* __restrict__ Ws,
                                 const float* __restrict__ Wv,
                                 const float* __restrict__ Wsc_s,
                                 const float* __restrict__ Wsc_v) {
    __shared__ float shx[8][128];  // s_in | v_in
    __shared__ float sha[8][128];  // agg_s | agg_v
    int t = threadIdx.x;
    int node0 = blockIdx.x * 8;
    #pragma unroll
    for (int k = 0; k < 4; ++k) {
        int idx = t + k * 256;
        int n = idx >> 7, col = idx & 127;
        int gn = node0 + n;
        if (gn < NN) {
            shx[n][col] = x[gn * 128 + col];
            sha[n][col] = (col < 32) ? agg_s[gn * 32 + col]
                                     : agg_v[gn * 96 + (col - 32)];
        }
    }
    __syncthreads();
    int n = t >> 5, f = t & 31;
    int gn = node0 + n;
    if (gn >= NN) return;

    float az0 = attrs[gn * 4 + 0], az1 = attrs[gn * 4 + 1];
    float az2 = attrs[gn * 4 + 2], az3 = attrs[gn * 4 + 3];

    float os0 = 0.f, os1 = 0.f;           // out_s[f], out_s[32+f]
    float ov0 = 0.f, ov1 = 0.f, ov2 = 0.f;

    #pragma unroll 4
    for (int c = 0; c < Cc; ++c) {
        float as = sha[n][c];
        os0 = fmaf(as, Ws[c * 64 + f], os0);
        os1 = fmaf(as, Ws[c * 64 + 32 + f], os1);

        float av0 = sha[n][32 + c * 3 + 0];
        float av1 = sha[n][32 + c * 3 + 1];
        float av2 = sha[n][32 + c * 3 + 2];
        float wv = Wv[c * 32 + f];
        ov0 = fmaf(av0, wv, ov0);
        ov1 = fmaf(av1, wv, ov1);
        ov2 = fmaf(av2, wv, ov2);

        float sc  = shx[n][c];
        float vi0 = shx[n][32 + c * 3 + 0];
        float vi1 = shx[n][32 + c * 3 + 1];
        float vi2 = shx[n][32 + c * 3 + 2];

        #pragma unroll
        for (int z = 0; z < 4; ++z) {
            float azv = (z == 0) ? az0 : (z == 1) ? az1 : (z == 2) ? az2 : az3;
            int cz = c * 4 + z;
            float wss0 = Wsc_s[cz * 64 + f];
            float wss1 = Wsc_s[cz * 64 + 32 + f];
            float wsv  = Wsc_v[cz * 32 + f];
            float sa = sc * azv;
            os0 = fmaf(sa, wss0, os0);
            os1 = fmaf(sa, wss1, os1);
            float va = azv * wsv;
            ov0 = fmaf(vi0, va, ov0);
            ov1 = fmaf(vi1, va, ov1);
            ov2 = fmaf(vi2, va, ov2);
        }
    }
    float feat = ssp_f(os0);
    float gate = ssp_f(os1);
    x[gn * 128 + f] += feat;
    x[gn * 128 + 32 + f * 3 + 0] += ov0 * gate;
    x[gn * 128 + 32 + f * 3 + 1] += ov1 * gate;
    x[gn * 128 + 32 + f * 3 + 2] += ov2 * gate;
}

extern "C" void kernel_launch(void* const* d_in, const int* in_sizes, int n_in,
                              void* d_out, int out_size, void* d_ws, size_t ws_size,
                              hipStream_t stream) {
    const float* node_features  = (const float*)d_in[0];
    const float* node_attrs     = (const float*)d_in[1];
    const int*   edge_index     = (const int*)d_in[2];
    const float* edge_embedding = (const float*)d_in[3];
    const float* edge_attrs     = (const float*)d_in[4];
    const float* W0    = (const float*)d_in[5];
    const float* W1    = (const float*)d_in[6];
    const float* Wr1   = (const float*)d_in[7];
    const float* Wr2   = (const float*)d_in[8];
    const float* Ws    = (const float*)d_in[9];
    const float* Wv    = (const float*)d_in[10];
    const float* Wsc_s = (const float*)d_in[11];
    const float* Wsc_v = (const float*)d_in[12];

    float* x = (float*)d_out;            // running node features, N x 128
    float* ws = (float*)d_ws;
    float* s_buf   = ws;                 // N*32
    float* v_buf   = s_buf + (size_t)NN * 32;   // N*96
    float* agg_s   = v_buf + (size_t)NN * 96;   // N*32
    float* agg_v   = agg_s + (size_t)NN * 32;   // N*96 (contiguous with agg_s)

    // x = node_features
    hipMemcpyAsync(x, node_features, (size_t)NN * 128 * sizeof(float),
                   hipMemcpyDeviceToDevice, stream);

    for (int l = 0; l < NL; ++l) {
        // zero agg_s + agg_v (contiguous N*128 floats)
        hipMemsetAsync(agg_s, 0, (size_t)NN * 128 * sizeof(float), stream);

        node_pre_kernel<<<NN / 8, 256, 0, stream>>>(
            x, W0 + l * Cc * Cc, W1 + l * Cc * Cc, s_buf, v_buf);

        edge_kernel<<<NE / 8, 256, 0, stream>>>(
            edge_index, edge_embedding, edge_attrs, s_buf, v_buf,
            Wr1 + l * Bb * Bb, Wr2 + l * Bb * 5 * Cc, agg_s, agg_v);

        node_post_kernel<<<NN / 8, 256, 0, stream>>>(
            x, node_attrs, agg_s, agg_v,
            Ws + l * Cc * 2 * Cc, Wv + l * Cc * Cc,
            Wsc_s + l * Cc * Zz * 2 * Cc, Wsc_v + l * Cc * Zz * Cc);
    }
}

// Round 2
// 728.742 us; speedup vs baseline: 2.6512x; 2.6512x over previous
//
#include <hip/hip_runtime.h>
#include <math.h>

#define NN 50000
#define NE 800000
#define Cc 32
#define Zz 4
#define Bb 8
#define NL 2
#define DEG_INV (1.0f/16.0f)

__device__ __forceinline__ float ssp_f(float x) {
    float sp = fmaxf(x, 0.0f) + log1pf(expf(-fabsf(x)));
    return sp - 0.69314718055994530942f;
}
__device__ __forceinline__ float silu_f(float x) {
    return x / (1.0f + expf(-x));
}

// ---------------- CSR build (once per call) ----------------

__global__ void hist_kernel(const int* __restrict__ ei, int* __restrict__ counts) {
    int e = blockIdx.x * 256 + threadIdx.x;
    if (e < NE) atomicAdd(&counts[ei[NE + e]], 1);
}

// 1 block, 1024 threads: exclusive scan of counts[NN] -> base[NN+1], copy to cursor
__global__ void scan_kernel(const int* __restrict__ counts,
                            int* __restrict__ base,
                            int* __restrict__ cursor) {
    __shared__ int partial[1024];
    int t = threadIdx.x;
    const int CH = 49;                 // 1024*49 >= 50000
    int b0 = t * CH, b1 = min(b0 + CH, NN);
    int sum = 0;
    for (int i = b0; i < b1; ++i) sum += counts[i];
    partial[t] = sum;
    __syncthreads();
    for (int off = 1; off < 1024; off <<= 1) {
        int v = 0;
        if (t >= off) v = partial[t - off];
        __syncthreads();
        if (t >= off) partial[t] += v;
        __syncthreads();
    }
    int prefix = (t == 0) ? 0 : partial[t - 1];
    for (int i = b0; i < b1; ++i) {
        base[i] = prefix;
        cursor[i] = prefix;
        prefix += counts[i];
    }
    if (t == 1023) base[NN] = prefix;
}

__global__ void scatter_kernel(const int* __restrict__ ei,
                               int* __restrict__ cursor,
                               int* __restrict__ perm_src,
                               int* __restrict__ perm_e) {
    int e = blockIdx.x * 256 + threadIdx.x;
    if (e >= NE) return;
    int dst = ei[NE + e];
    int pos = atomicAdd(&cursor[dst], 1);
    perm_src[pos] = ei[e];
    perm_e[pos] = e;
}

// ---------------- per-layer kernels ----------------

// sv[n][0..31]=s, sv[n][32+c*3+i]=v
__global__ void node_pre_kernel(const float* __restrict__ x,
                                const float* __restrict__ W0,
                                const float* __restrict__ W1,
                                float* __restrict__ sv) {
    __shared__ float xs[8][128];
    int t = threadIdx.x;
    int node0 = blockIdx.x * 8;
    #pragma unroll
    for (int k = 0; k < 4; ++k) {
        int idx = t + k * 256;
        int n = idx >> 7, col = idx & 127;
        xs[n][col] = x[(size_t)(node0 + n) * 128 + col];
    }
    __syncthreads();
    int n = t >> 5, f = t & 31;
    int gn = node0 + n;
    float acc_s = 0.f, a0 = 0.f, a1 = 0.f, a2 = 0.f;
    #pragma unroll
    for (int c = 0; c < Cc; ++c) {
        float w0 = W0[c * Cc + f];
        float w1 = W1[c * Cc + f];
        acc_s = fmaf(xs[n][c], w0, acc_s);
        a0 = fmaf(xs[n][32 + c * 3 + 0], w1, a0);
        a1 = fmaf(xs[n][32 + c * 3 + 1], w1, a1);
        a2 = fmaf(xs[n][32 + c * 3 + 2], w1, a2);
    }
    float* o = sv + (size_t)gn * 128;
    o[f] = acc_s;
    o[32 + f * 3 + 0] = a0;
    o[32 + f * 3 + 1] = a1;
    o[32 + f * 3 + 2] = a2;
}

// per sorted slot: h = silu(emb[e] @ Wr1), hY[pos] = {h[0..7], Y0, Yv0, Yv1, Yv2}
__global__ void edge_pre_kernel(const int* __restrict__ perm_e,
                                const float* __restrict__ emb,
                                const float* __restrict__ eattr,
                                const float* __restrict__ Wr1,
                                float* __restrict__ hY) {
    __shared__ float wr1s[64];
    int t = threadIdx.x;
    if (t < 64) wr1s[t] = Wr1[t];
    __syncthreads();
    int pos = blockIdx.x * 256 + t;
    if (pos >= NE) return;
    int e = perm_e[pos];
    const float4* em4 = (const float4*)(emb + (size_t)e * 8);
    float4 e0 = em4[0], e1 = em4[1];
    float em[8] = {e0.x, e0.y, e0.z, e0.w, e1.x, e1.y, e1.z, e1.w};
    float h[8];
    #pragma unroll
    for (int j = 0; j < 8; ++j) {
        float a = 0.f;
        #pragma unroll
        for (int k = 0; k < 8; ++k) a = fmaf(em[k], wr1s[k * 8 + j], a);
        h[j] = silu_f(a);
    }
    float4 Y = ((const float4*)eattr)[e];
    float4* out = (float4*)(hY + (size_t)pos * 12);
    out[0] = make_float4(h[0], h[1], h[2], h[3]);
    out[1] = make_float4(h[4], h[5], h[6], h[7]);
    out[2] = Y;
}

// one 32-lane group per dst node; walks its contiguous CSR segment; no atomics
__global__ void agg_kernel(const int* __restrict__ base,
                           const int* __restrict__ perm_src,
                           const float* __restrict__ hY,
                           const float* __restrict__ sv,
                           const float* __restrict__ Wr2,
                           float* __restrict__ agg) {
    __shared__ float wr2s[8][160];
    int t = threadIdx.x;
    for (int i = t; i < 8 * 160; i += 256) ((float*)wr2s)[i] = Wr2[i];
    __syncthreads();
    int n = blockIdx.x * 8 + (t >> 5);
    int c = t & 31;
    int jb = base[n], je = base[n + 1];
    float ms = 0.f, mv0 = 0.f, mv1 = 0.f, mv2 = 0.f;
    for (int j = jb; j < je; ++j) {
        int src = perm_src[j];
        const float4* hy4 = (const float4*)(hY + (size_t)j * 12);
        float4 ha = hy4[0], hb = hy4[1], Y = hy4[2];
        float h[8] = {ha.x, ha.y, ha.z, ha.w, hb.x, hb.y, hb.z, hb.w};
        float w1 = 0.f, w2 = 0.f, w3 = 0.f, w4 = 0.f, w5 = 0.f;
        #pragma unroll
        for (int k = 0; k < 8; ++k) {
            float hk = h[k];
            w1 = fmaf(hk, wr2s[k][c], w1);
            w2 = fmaf(hk, wr2s[k][32 + c], w2);
            w3 = fmaf(hk, wr2s[k][64 + c], w3);
            w4 = fmaf(hk, wr2s[k][96 + c], w4);
            w5 = fmaf(hk, wr2s[k][128 + c], w5);
        }
        const float* svp = sv + (size_t)src * 128;
        float se  = svp[c];
        float ve0 = svp[32 + c * 3 + 0];
        float ve1 = svp[32 + c * 3 + 1];
        float ve2 = svp[32 + c * 3 + 2];

        float dot = ve0 * Y.y + ve1 * Y.z + ve2 * Y.w;
        ms += w1 * se * Y.x + w4 * dot;

        float cx = ve1 * Y.w - ve2 * Y.z;
        float cy = ve2 * Y.y - ve0 * Y.w;
        float cz = ve0 * Y.z - ve1 * Y.y;

        mv0 += w2 * se * Y.y + w3 * ve0 * Y.x + w5 * cx;
        mv1 += w2 * se * Y.z + w3 * ve1 * Y.x + w5 * cy;
        mv2 += w2 * se * Y.w + w3 * ve2 * Y.x + w5 * cz;
    }
    float* ap = agg + (size_t)n * 128;
    ap[c] = ms * DEG_INV;
    ap[32 + c * 3 + 0] = mv0 * DEG_INV;
    ap[32 + c * 3 + 1] = mv1 * DEG_INV;
    ap[32 + c * 3 + 2] = mv2 * DEG_INV;
}

// fallback (atomic) edge kernel, combined sv/agg layout
__global__ void edge_atomic_kernel(const int* __restrict__ ei,
                                   const float* __restrict__ emb,
                                   const float* __restrict__ eattr,
                                   const float* __restrict__ sv,
                                   const float* __restrict__ Wr1,
                                   const float* __restrict__ Wr2,
                                   float* __restrict__ agg) {
    int t = threadIdx.x;
    int eg = t >> 5;
    int c = t & 31;
    int e = blockIdx.x * 8 + eg;
    if (e >= NE) return;
    int src = ei[e];
    int dst = ei[NE + e];
    float h = 0.f;
    if (c < 8) {
        #pragma unroll
        for (int k = 0; k < 8; ++k)
            h = fmaf(emb[e * 8 + k], Wr1[k * 8 + c], h);
        h = silu_f(h);
    }
    float w1 = 0.f, w2 = 0.f, w3 = 0.f, w4 = 0.f, w5 = 0.f;
    #pragma unroll
    for (int j = 0; j < 8; ++j) {
        float hj = __shfl(h, j, 32);
        const float* wr = Wr2 + j * 160;
        w1 = fmaf(hj, wr[c], w1);
        w2 = fmaf(hj, wr[32 + c], w2);
        w3 = fmaf(hj, wr[64 + c], w3);
        w4 = fmaf(hj, wr[96 + c], w4);
        w5 = fmaf(hj, wr[128 + c], w5);
    }
    float Y0  = eattr[e * 4 + 0];
    float Yv0 = eattr[e * 4 + 1];
    float Yv1 = eattr[e * 4 + 2];
    float Yv2 = eattr[e * 4 + 3];
    const float* svp = sv + (size_t)src * 128;
    float se  = svp[c];
    float ve0 = svp[32 + c * 3 + 0];
    float ve1 = svp[32 + c * 3 + 1];
    float ve2 = svp[32 + c * 3 + 2];
    float dot = ve0 * Yv0 + ve1 * Yv1 + ve2 * Yv2;
    float ms = (w1 * se * Y0 + w4 * dot) * DEG_INV;
    float cx = ve1 * Yv2 - ve2 * Yv1;
    float cy = ve2 * Yv0 - ve0 * Yv2;
    float cz = ve0 * Yv1 - ve1 * Yv0;
    float mv0 = (w2 * se * Yv0 + w3 * ve0 * Y0 + w5 * cx) * DEG_INV;
    float mv1 = (w2 * se * Yv1 + w3 * ve1 * Y0 + w5 * cy) * DEG_INV;
    float mv2 = (w2 * se * Yv2 + w3 * ve2 * Y0 + w5 * cz) * DEG_INV;
    float* ap = agg + (size_t)dst * 128;
    atomicAdd(&ap[c], ms);
    atomicAdd(&ap[32 + c * 3 + 0], mv0);
    atomicAdd(&ap[32 + c * 3 + 1], mv1);
    atomicAdd(&ap[32 + c * 3 + 2], mv2);
}

__global__ void node_post_kernel(float* __restrict__ x,
                                 const float* __restrict__ attrs,
                                 const float* __restrict__ agg,
                                 const float* __restrict__ Ws,
                                 const float* __restrict__ Wv,
                                 const float* __restrict__ Wsc_s,
                                 const float* __restrict__ Wsc_v) {
    __shared__ float shx[8][128];
    __shared__ float sha[8][128];
    int t = threadIdx.x;
    int node0 = blockIdx.x * 8;
    #pragma unroll
    for (int k = 0; k < 4; ++k) {
        int idx = t + k * 256;
        int n = idx >> 7, col = idx & 127;
        int gn = node0 + n;
        shx[n][col] = x[(size_t)gn * 128 + col];
        sha[n][col] = agg[(size_t)gn * 128 + col];
    }
    __syncthreads();
    int n = t >> 5, f = t & 31;
    int gn = node0 + n;

    float az0 = attrs[gn * 4 + 0], az1 = attrs[gn * 4 + 1];
    float az2 = attrs[gn * 4 + 2], az3 = attrs[gn * 4 + 3];

    float os0 = 0.f, os1 = 0.f;
    float ov0 = 0.f, ov1 = 0.f, ov2 = 0.f;

    #pragma unroll 4
    for (int c = 0; c < Cc; ++c) {
        float as = sha[n][c];
        os0 = fmaf(as, Ws[c * 64 + f], os0);
        os1 = fmaf(as, Ws[c * 64 + 32 + f], os1);

        float av0 = sha[n][32 + c * 3 + 0];
        float av1 = sha[n][32 + c * 3 + 1];
        float av2 = sha[n][32 + c * 3 + 2];
        float wv = Wv[c * 32 + f];
        ov0 = fmaf(av0, wv, ov0);
        ov1 = fmaf(av1, wv, ov1);
        ov2 = fmaf(av2, wv, ov2);

        float sc  = shx[n][c];
        float vi0 = shx[n][32 + c * 3 + 0];
        float vi1 = shx[n][32 + c * 3 + 1];
        float vi2 = shx[n][32 + c * 3 + 2];

        #pragma unroll
        for (int z = 0; z < 4; ++z) {
            float azv = (z == 0) ? az0 : (z == 1) ? az1 : (z == 2) ? az2 : az3;
            int cz = c * 4 + z;
            float sa = sc * azv;
            os0 = fmaf(sa, Wsc_s[cz * 64 + f], os0);
            os1 = fmaf(sa, Wsc_s[cz * 64 + 32 + f], os1);
            float va = azv * Wsc_v[cz * 32 + f];
            ov0 = fmaf(vi0, va, ov0);
            ov1 = fmaf(vi1, va, ov1);
            ov2 = fmaf(vi2, va, ov2);
        }
    }
    float feat = ssp_f(os0);
    float gate = ssp_f(os1);
    float* xp = x + (size_t)gn * 128;
    xp[f] += feat;
    xp[32 + f * 3 + 0] += ov0 * gate;
    xp[32 + f * 3 + 1] += ov1 * gate;
    xp[32 + f * 3 + 2] += ov2 * gate;
}

extern "C" void kernel_launch(void* const* d_in, const int* in_sizes, int n_in,
                              void* d_out, int out_size, void* d_ws, size_t ws_size,
                              hipStream_t stream) {
    const float* node_features  = (const float*)d_in[0];
    const float* node_attrs     = (const float*)d_in[1];
    const int*   edge_index     = (const int*)d_in[2];
    const float* edge_embedding = (const float*)d_in[3];
    const float* edge_attrs     = (const float*)d_in[4];
    const float* W0    = (const float*)d_in[5];
    const float* W1    = (const float*)d_in[6];
    const float* Wr1   = (const float*)d_in[7];
    const float* Wr2   = (const float*)d_in[8];
    const float* Ws    = (const float*)d_in[9];
    const float* Wv    = (const float*)d_in[10];
    const float* Wsc_s = (const float*)d_in[11];
    const float* Wsc_v = (const float*)d_in[12];

    float* x = (float*)d_out;

    float* ws = (float*)d_ws;
    float* sv  = ws;                                  // NN*128
    float* agg = sv + (size_t)NN * 128;               // NN*128
    int* counts   = (int*)(agg + (size_t)NN * 128);   // NN
    int* base     = counts + NN;                      // NN+1
    int* cursor   = base + NN + 1;                    // NN
    int* perm_src = cursor + NN;                      // NE
    int* perm_e   = perm_src + NE;                    // NE
    float* hY     = (float*)(perm_e + NE);            // NE*12
    size_t needed = ((char*)(hY + (size_t)NE * 12)) - (char*)d_ws;

    hipMemcpyAsync(x, node_features, (size_t)NN * 128 * sizeof(float),
                   hipMemcpyDeviceToDevice, stream);

    bool use_sorted = ws_size >= needed;

    if (use_sorted) {
        hipMemsetAsync(counts, 0, NN * sizeof(int), stream);
        hist_kernel<<<NE / 256, 256, 0, stream>>>(edge_index, counts);
        scan_kernel<<<1, 1024, 0, stream>>>(counts, base, cursor);
        scatter_kernel<<<NE / 256, 256, 0, stream>>>(edge_index, cursor, perm_src, perm_e);

        for (int l = 0; l < NL; ++l) {
            node_pre_kernel<<<NN / 8, 256, 0, stream>>>(
                x, W0 + l * Cc * Cc, W1 + l * Cc * Cc, sv);
            edge_pre_kernel<<<NE / 256, 256, 0, stream>>>(
                perm_e, edge_embedding, edge_attrs, Wr1 + l * Bb * Bb, hY);
            agg_kernel<<<NN / 8, 256, 0, stream>>>(
                base, perm_src, hY, sv, Wr2 + l * Bb * 5 * Cc, agg);
            node_post_kernel<<<NN / 8, 256, 0, stream>>>(
                x, node_attrs, agg,
                Ws + l * Cc * 2 * Cc, Wv + l * Cc * Cc,
                Wsc_s + l * Cc * Zz * 2 * Cc, Wsc_v + l * Cc * Zz * Cc);
        }
    } else {
        for (int l = 0; l < NL; ++l) {
            hipMemsetAsync(agg, 0, (size_t)NN * 128 * sizeof(float), stream);
            node_pre_kernel<<<NN / 8, 256, 0, stream>>>(
                x, W0 + l * Cc * Cc, W1 + l * Cc * Cc, sv);
            edge_atomic_kernel<<<NE / 8, 256, 0, stream>>>(
                edge_index, edge_embedding, edge_attrs, sv,
                Wr1 + l * Bb * Bb, Wr2 + l * Bb * 5 * Cc, agg);
            node_post_kernel<<<NN / 8, 256, 0, stream>>>(
                x, node_attrs, agg,
                Ws + l * Cc * 2 * Cc, Wv + l * Cc * Cc,
                Wsc_s + l * Cc * Zz * 2 * Cc, Wsc_v + l * Cc * Zz * Cc);
        }
    }
}